// Round 2
// baseline (19945.322 us; speedup 1.0000x reference)
//
#include <hip/hip_runtime.h>
#include <cstdint>
#include <cstddef>

// GRU-D: B=64, T=512, D=256, H=1024.
// v2: persistent-kernel scan. 256 WGs (1/CU), U slices resident in LDS,
// MFMA 16x16x32 f16 recurrent GEMMs, 2 device-scope grid barriers per step.

#define NB 64
#define NT 512
#define ND 256
#define NH 1024

typedef _Float16 h2_t __attribute__((ext_vector_type(2)));
typedef _Float16 half8 __attribute__((ext_vector_type(8)));
typedef float f32x4 __attribute__((ext_vector_type(4)));

__device__ __forceinline__ float fdot2(uint32_t a, uint32_t b, float acc) {
  h2_t ha = __builtin_bit_cast(h2_t, a);
  h2_t hb = __builtin_bit_cast(h2_t, b);
#if __has_builtin(__builtin_amdgcn_fdot2)
  return __builtin_amdgcn_fdot2(ha, hb, acc, false);
#else
  return acc + (float)ha[0] * (float)hb[0] + (float)ha[1] * (float)hb[1];
#endif
}

__device__ __forceinline__ uint32_t pack2(float a, float b) {
  h2_t v; v[0] = (_Float16)a; v[1] = (_Float16)b;
  return __builtin_bit_cast(uint32_t, v);
}
__device__ __forceinline__ uint16_t f2h(float x) {
  _Float16 v = (_Float16)x; return __builtin_bit_cast(uint16_t, v);
}
__device__ __forceinline__ float h2f(uint16_t u) {
  return (float)__builtin_bit_cast(_Float16, u);
}

// ---- pack kernels ------------------------------------------------------

__global__ void pack_x_k(const float2* __restrict__ x, uint32_t* __restrict__ x2, int n) {
  int stride = gridDim.x * blockDim.x;
  for (int i = blockIdx.x * blockDim.x + threadIdx.x; i < n; i += stride) {
    float2 v = x[i];
    x2[i] = pack2(v.x, v.y);
  }
}

// src [K][1024] f32 -> dst [K/2][1024] f16x2 (pairs along K)
__global__ void pack_rows_k(const float* __restrict__ src, uint32_t* __restrict__ dst, int K) {
  int n = (K >> 1) * NH;
  int stride = gridDim.x * blockDim.x;
  for (int i = blockIdx.x * blockDim.x + threadIdx.x; i < n; i += stride) {
    int kp = i >> 10, j = i & 1023;
    dst[i] = pack2(src[(2 * kp) * NH + j], src[(2 * kp + 1) * NH + j]);
  }
}

// ---- phase 1: input projections (unchanged from v1, works) -------------
__global__ __launch_bounds__(256) void proj_k(
    const uint32_t* __restrict__ x2, const uint32_t* __restrict__ W2,
    const float* __restrict__ bd, const float* __restrict__ bz,
    const float* __restrict__ br, const float* __restrict__ bh,
    uint16_t* __restrict__ g_gamma, uint16_t* __restrict__ g_xz,
    uint16_t* __restrict__ g_xr, uint16_t* __restrict__ g_xh) {
  __shared__ uint32_t xs[64 * 132];
  int wg = blockIdx.x;
  int rg = wg >> 6;
  int cg = wg & 63;
  int tid = threadIdx.x;

  const uint4* xsrc = (const uint4*)x2 + (size_t)rg * 64 * 32;
#pragma unroll
  for (int w = 0; w < 8; ++w) {
    int f = tid + w * 256;
    int row = f >> 5, q = f & 31;
    *(uint4*)&xs[row * 132 + q * 4] = xsrc[row * 32 + q];
  }
  __syncthreads();

  int a = cg >> 4;
  int j0 = (cg & 15) * 64 + (tid & 15) * 4;
  int tr = tid >> 4;
  const uint32_t* W2a = W2 + (size_t)a * (128 * 1024) + j0;

  float acc[4][4] = {};
#pragma unroll 4
  for (int kp = 0; kp < 128; ++kp) {
    uint32_t xv0 = xs[(tr * 4 + 0) * 132 + kp];
    uint32_t xv1 = xs[(tr * 4 + 1) * 132 + kp];
    uint32_t xv2 = xs[(tr * 4 + 2) * 132 + kp];
    uint32_t xv3 = xs[(tr * 4 + 3) * 132 + kp];
    uint4 wv = *(const uint4*)(W2a + (size_t)kp * 1024);
    acc[0][0] = fdot2(xv0, wv.x, acc[0][0]); acc[0][1] = fdot2(xv0, wv.y, acc[0][1]);
    acc[0][2] = fdot2(xv0, wv.z, acc[0][2]); acc[0][3] = fdot2(xv0, wv.w, acc[0][3]);
    acc[1][0] = fdot2(xv1, wv.x, acc[1][0]); acc[1][1] = fdot2(xv1, wv.y, acc[1][1]);
    acc[1][2] = fdot2(xv1, wv.z, acc[1][2]); acc[1][3] = fdot2(xv1, wv.w, acc[1][3]);
    acc[2][0] = fdot2(xv2, wv.x, acc[2][0]); acc[2][1] = fdot2(xv2, wv.y, acc[2][1]);
    acc[2][2] = fdot2(xv2, wv.z, acc[2][2]); acc[2][3] = fdot2(xv2, wv.w, acc[2][3]);
    acc[3][0] = fdot2(xv3, wv.x, acc[3][0]); acc[3][1] = fdot2(xv3, wv.y, acc[3][1]);
    acc[3][2] = fdot2(xv3, wv.z, acc[3][2]); acc[3][3] = fdot2(xv3, wv.w, acc[3][3]);
  }

  const float* bias = a == 0 ? bd : a == 1 ? bz : a == 2 ? br : bh;
  uint16_t* dst = a == 0 ? g_gamma : a == 1 ? g_xz : a == 2 ? g_xr : g_xh;
  float b0 = bias[j0], b1 = bias[j0 + 1], b2 = bias[j0 + 2], b3 = bias[j0 + 3];
#pragma unroll
  for (int i = 0; i < 4; ++i) {
    int n = rg * 64 + tr * 4 + i;
    int b = n >> 9, t = n & 511;
    float p0 = acc[i][0] + b0, p1 = acc[i][1] + b1;
    float p2 = acc[i][2] + b2, p3 = acc[i][3] + b3;
    if (a == 0) {
      p0 = __expf(-fmaxf(p0, 0.f)); p1 = __expf(-fmaxf(p1, 0.f));
      p2 = __expf(-fmaxf(p2, 0.f)); p3 = __expf(-fmaxf(p3, 0.f));
    }
    uint32_t* o = (uint32_t*)(dst + (((size_t)(t * 64 + b)) << 10) + j0);
    o[0] = pack2(p0, p1);
    o[1] = pack2(p2, p3);
  }
}

// ---- persistent scan kernel -------------------------------------------
// 256 WGs x 256 threads. WG wg owns output tile rows [rt*16,+16) x cols
// [c*16,+16), rt = wg&3, c = wg>>2. U col-slices (transposed, f16) live in
// LDS for the whole scan. Per step: P1 computes z (wave0/1) and
// rh = sigmoid(xr+h@Ur)*h (wave2/3) -> RH global; grid barrier; P2 computes
// hprop via RH@Uh (all 4 waves K-split), combines, writes out + hdec(t+1);
// grid barrier.

__device__ __forceinline__ void gbar(unsigned* cnt, unsigned target) {
  __syncthreads();  // drains vmcnt for all waves before arrival
  if (threadIdx.x == 0) {
    __threadfence();  // agent-scope release: make our writes visible
    __hip_atomic_fetch_add(cnt, 1u, __ATOMIC_RELAXED, __HIP_MEMORY_SCOPE_AGENT);
    while (__hip_atomic_load(cnt, __ATOMIC_RELAXED, __HIP_MEMORY_SCOPE_AGENT) < target)
      __builtin_amdgcn_s_sleep(1);
    __threadfence();  // agent-scope acquire: invalidate caches
  }
  __syncthreads();
}

#define UT_STRIDE 1032  // halves per col row (1024 + 8 pad -> 516 dwords, bank-spread)

__global__ __launch_bounds__(256) void scan_k(
    const float* __restrict__ Uz, const float* __restrict__ Ur,
    const float* __restrict__ Uh,
    const uint16_t* __restrict__ g_gamma, const uint16_t* __restrict__ g_xz,
    const uint16_t* __restrict__ g_xr, const uint16_t* __restrict__ g_xh,
    uint16_t* __restrict__ hdec, uint16_t* __restrict__ RH,
    float* __restrict__ out, unsigned* __restrict__ cnt) {
  __shared__ uint16_t lds[4 * 16 * UT_STRIDE + 1536];  // 3 U slices + hs + red
  float* red = (float*)(lds + 4 * 16 * UT_STRIDE);

  const int tid = threadIdx.x;
  const int wg = blockIdx.x;
  const int rt = wg & 3;
  const int c = wg >> 2;
  const int lane = tid & 63, wv = tid >> 6;
  const int r16 = lane & 15, q = lane >> 4;

  // one-time: stage U col-slices transposed (Ut[col][k], f16)
  {
    const float* Us[3] = {Uz, Ur, Uh};
#pragma unroll
    for (int m = 0; m < 3; ++m) {
      uint16_t* ut = lds + m * (16 * UT_STRIDE);
      const float* src = Us[m] + c * 16;
      for (int i = tid; i < 16 * 1024; i += 256) {
        int k = i >> 4, col = i & 15;
        ut[col * UT_STRIDE + k] = f2h(src[(size_t)k * 1024 + col]);
      }
    }
  }

  uint16_t* hs = lds + 3 * (16 * UT_STRIDE);
  const uint16_t* utz = lds;
  const uint16_t* utr = lds + 16 * UT_STRIDE;
  const uint16_t* uth = lds + 2 * (16 * UT_STRIDE);

  unsigned target = 0;
  f32x4 zacc = {0.f, 0.f, 0.f, 0.f};
  const int col = c * 16 + r16;

  for (int t = 0; t < NT; ++t) {
    // ---- P1: stage hdec rows [rt*16,+16) into hs ----
    {
      const uint4* src = (const uint4*)hdec + (size_t)(rt * 16) * 128;
#pragma unroll
      for (int i = 0; i < 8; ++i) {
        int f = tid + i * 256;
        int row = f >> 7, qq = f & 127;
        *(uint4*)&hs[row * UT_STRIDE + qq * 8] = src[row * 128 + qq];
      }
    }
    __syncthreads();

    int zr = wv >> 1, kh = wv & 1;
    const uint16_t* ub = (zr == 0) ? utz : utr;
    f32x4 acc = {0.f, 0.f, 0.f, 0.f};
    {
      const uint16_t* ap = hs + r16 * UT_STRIDE + kh * 512 + q * 8;
      const uint16_t* bp = ub + r16 * UT_STRIDE + kh * 512 + q * 8;
#pragma unroll
      for (int ks = 0; ks < 16; ++ks) {
        half8 av = *(const half8*)(ap + ks * 32);
        half8 bv = *(const half8*)(bp + ks * 32);
        acc = __builtin_amdgcn_mfma_f32_16x16x32_f16(av, bv, acc, 0, 0, 0);
      }
    }
    if (kh == 1) {
#pragma unroll
      for (int j = 0; j < 4; ++j) red[zr * 256 + j * 64 + lane] = acc[j];
    }
    __syncthreads();
    if (kh == 0) {
#pragma unroll
      for (int j = 0; j < 4; ++j) acc[j] += red[zr * 256 + j * 64 + lane];
      if (zr == 0) {  // z gate -> registers
#pragma unroll
        for (int j = 0; j < 4; ++j) {
          int b = rt * 16 + q * 4 + j;
          float xz = h2f(g_xz[(((size_t)(t * 64 + b)) << 10) + col]);
          zacc[j] = 1.f / (1.f + __expf(-(xz + acc[j])));
        }
      } else {  // r gate -> RH = r * hdec -> global
#pragma unroll
        for (int j = 0; j < 4; ++j) {
          int b = rt * 16 + q * 4 + j;
          float xr = h2f(g_xr[(((size_t)(t * 64 + b)) << 10) + col]);
          float s = 1.f / (1.f + __expf(-(xr + acc[j])));
          float hd = h2f(hs[(q * 4 + j) * UT_STRIDE + col]);
          RH[(size_t)b * 1024 + col] = f2h(s * hd);
        }
      }
    }
    target += 256;
    gbar(cnt, target);

    // ---- P2: stage RH rows, Uh GEMM, combine ----
    {
      const uint4* src = (const uint4*)RH + (size_t)(rt * 16) * 128;
#pragma unroll
      for (int i = 0; i < 8; ++i) {
        int f = tid + i * 256;
        int row = f >> 7, qq = f & 127;
        *(uint4*)&hs[row * UT_STRIDE + qq * 8] = src[row * 128 + qq];
      }
    }
    __syncthreads();

    f32x4 acc2 = {0.f, 0.f, 0.f, 0.f};
    {
      const uint16_t* ap = hs + r16 * UT_STRIDE + wv * 256 + q * 8;
      const uint16_t* bp = uth + r16 * UT_STRIDE + wv * 256 + q * 8;
#pragma unroll
      for (int ks = 0; ks < 8; ++ks) {
        half8 av = *(const half8*)(ap + ks * 32);
        half8 bv = *(const half8*)(bp + ks * 32);
        acc2 = __builtin_amdgcn_mfma_f32_16x16x32_f16(av, bv, acc2, 0, 0, 0);
      }
    }
    if (wv != 0) {
#pragma unroll
      for (int j = 0; j < 4; ++j) red[(wv - 1) * 256 + j * 64 + lane] = acc2[j];
    }
    __syncthreads();
    if (wv == 0) {
#pragma unroll
      for (int j = 0; j < 4; ++j) {
        float s = acc2[j] + red[j * 64 + lane] + red[256 + j * 64 + lane] +
                  red[512 + j * 64 + lane];
        int b = rt * 16 + q * 4 + j;
        size_t tb = (((size_t)(t * 64 + b)) << 10) + col;
        float hp = tanhf(h2f(g_xh[tb]) + s);
        float z = zacc[j];
        float hd = h2f(hdec[(size_t)b * 1024 + col]);
        float h = (1.f - z) * hd + z * hp;
        out[((size_t)b * NT + t) * NH + col] = h;
        if (t + 1 < NT) {
          float g = h2f(g_gamma[(((size_t)((t + 1) * 64 + b)) << 10) + col]);
          hdec[(size_t)b * 1024 + col] = f2h(g * h);
        }
      }
    }
    if (t + 1 < NT) {
      target += 256;
      gbar(cnt, target);
    }
  }
}

// ---- launch ------------------------------------------------------------

extern "C" void kernel_launch(void* const* d_in, const int* in_sizes, int n_in,
                              void* d_out, int out_size, void* d_ws, size_t ws_size,
                              hipStream_t stream) {
  const float* x  = (const float*)d_in[0];
  const float* Wd = (const float*)d_in[1];
  const float* bd = (const float*)d_in[2];
  const float* Wz = (const float*)d_in[3];
  const float* Wr = (const float*)d_in[4];
  const float* Wh = (const float*)d_in[5];
  const float* Uz = (const float*)d_in[6];
  const float* Ur = (const float*)d_in[7];
  const float* Uh = (const float*)d_in[8];
  const float* bz = (const float*)d_in[9];
  const float* br = (const float*)d_in[10];
  const float* bh = (const float*)d_in[11];
  float* out = (float*)d_out;

  char* ws = (char*)d_ws;
  size_t off = 0;
  auto take = [&](size_t bytes) -> char* {
    char* p = ws + off;
    off = (off + bytes + 255) & ~(size_t)255;
    return p;
  };
  uint32_t* x2 = (uint32_t*)take((size_t)32768 * 128 * 4);    // 16 MiB
  uint32_t* W2 = (uint32_t*)take((size_t)4 * 128 * 1024 * 4); // 2 MiB
  uint16_t* g_gamma = (uint16_t*)take((size_t)NT * NB * NH * 2); // 64 MiB
  uint16_t* g_xz   = (uint16_t*)take((size_t)NT * NB * NH * 2);
  uint16_t* g_xr   = (uint16_t*)take((size_t)NT * NB * NH * 2);
  uint16_t* g_xh   = (uint16_t*)take((size_t)NT * NB * NH * 2);
  uint16_t* hdec   = (uint16_t*)take((size_t)NB * NH * 2);
  uint16_t* RHb    = (uint16_t*)take((size_t)NB * NH * 2);
  unsigned* cnt    = (unsigned*)take(256);
  (void)ws_size; (void)in_sizes; (void)n_in; (void)out_size;

  hipMemsetAsync(hdec, 0, (size_t)NB * NH * 2, stream);
  hipMemsetAsync(cnt, 0, 4, stream);

  pack_x_k<<<2048, 256, 0, stream>>>((const float2*)x, x2, 32768 * 128);
  pack_rows_k<<<512, 256, 0, stream>>>(Wd, W2 + 0 * (128 * 1024), ND);
  pack_rows_k<<<512, 256, 0, stream>>>(Wz, W2 + 1 * (128 * 1024), ND);
  pack_rows_k<<<512, 256, 0, stream>>>(Wr, W2 + 2 * (128 * 1024), ND);
  pack_rows_k<<<512, 256, 0, stream>>>(Wh, W2 + 3 * (128 * 1024), ND);

  proj_k<<<32768, 256, 0, stream>>>(x2, W2, bd, bz, br, bh,
                                    g_gamma, g_xz, g_xr, g_xh);

  scan_k<<<256, 256, 0, stream>>>(Uz, Ur, Uh, g_gamma, g_xz, g_xr, g_xh,
                                  hdec, RHb, out, cnt);
}

// Round 3
// 6152.785 us; speedup vs baseline: 3.2417x; 3.2417x over previous
//
#include <hip/hip_runtime.h>
#include <cstdint>
#include <cstddef>

// GRU-D: B=64, T=512, D=256, H=1024.
// v3: persistent scan, per-access coherent exchange (sc0 sc1), distributed
// flag barriers per 64-WG row group. No threadfence, no atomic RMW.

#define NB 64
#define NT 512
#define ND 256
#define NH 1024
#define UT_STRIDE 1032

typedef _Float16 h2_t __attribute__((ext_vector_type(2)));
typedef _Float16 half8 __attribute__((ext_vector_type(8)));
typedef float f32x4 __attribute__((ext_vector_type(4)));

__device__ __forceinline__ float fdot2(uint32_t a, uint32_t b, float acc) {
  h2_t ha = __builtin_bit_cast(h2_t, a);
  h2_t hb = __builtin_bit_cast(h2_t, b);
#if __has_builtin(__builtin_amdgcn_fdot2)
  return __builtin_amdgcn_fdot2(ha, hb, acc, false);
#else
  return acc + (float)ha[0] * (float)hb[0] + (float)ha[1] * (float)hb[1];
#endif
}

__device__ __forceinline__ uint32_t pack2(float a, float b) {
  h2_t v; v[0] = (_Float16)a; v[1] = (_Float16)b;
  return __builtin_bit_cast(uint32_t, v);
}
__device__ __forceinline__ uint16_t f2h(float x) {
  _Float16 v = (_Float16)x; return __builtin_bit_cast(uint16_t, v);
}
__device__ __forceinline__ float h2f(uint16_t u) {
  return (float)__builtin_bit_cast(_Float16, u);
}

// coherent (point-of-coherency) accesses: bypass L1/L2, hit MALL directly
__device__ __forceinline__ uint4 ld_cg_b128(const void* p) {
  uint4 v;
  asm volatile("global_load_dwordx4 %0, %1, off sc0 sc1" : "=v"(v) : "v"(p) : "memory");
  return v;
}
__device__ __forceinline__ void st_cg_b16(void* p, uint32_t v) {
  asm volatile("global_store_short %0, %1, off sc0 sc1" :: "v"(p), "v"(v) : "memory");
}

// ---- pack kernels ------------------------------------------------------

__global__ void pack_x_k(const float2* __restrict__ x, uint32_t* __restrict__ x2, int n) {
  int stride = gridDim.x * blockDim.x;
  for (int i = blockIdx.x * blockDim.x + threadIdx.x; i < n; i += stride) {
    float2 v = x[i];
    x2[i] = pack2(v.x, v.y);
  }
}

__global__ void pack_rows_k(const float* __restrict__ src, uint32_t* __restrict__ dst, int K) {
  int n = (K >> 1) * NH;
  int stride = gridDim.x * blockDim.x;
  for (int i = blockIdx.x * blockDim.x + threadIdx.x; i < n; i += stride) {
    int kp = i >> 10, j = i & 1023;
    dst[i] = pack2(src[(2 * kp) * NH + j], src[(2 * kp + 1) * NH + j]);
  }
}

// ---- phase 1: input projections (unchanged, proven) --------------------
__global__ __launch_bounds__(256) void proj_k(
    const uint32_t* __restrict__ x2, const uint32_t* __restrict__ W2,
    const float* __restrict__ bd, const float* __restrict__ bz,
    const float* __restrict__ br, const float* __restrict__ bh,
    uint16_t* __restrict__ g_gamma, uint16_t* __restrict__ g_xz,
    uint16_t* __restrict__ g_xr, uint16_t* __restrict__ g_xh) {
  __shared__ uint32_t xs[64 * 132];
  int wg = blockIdx.x;
  int rg = wg >> 6;
  int cg = wg & 63;
  int tid = threadIdx.x;

  const uint4* xsrc = (const uint4*)x2 + (size_t)rg * 64 * 32;
#pragma unroll
  for (int w = 0; w < 8; ++w) {
    int f = tid + w * 256;
    int row = f >> 5, q = f & 31;
    *(uint4*)&xs[row * 132 + q * 4] = xsrc[row * 32 + q];
  }
  __syncthreads();

  int a = cg >> 4;
  int j0 = (cg & 15) * 64 + (tid & 15) * 4;
  int tr = tid >> 4;
  const uint32_t* W2a = W2 + (size_t)a * (128 * 1024) + j0;

  float acc[4][4] = {};
#pragma unroll 4
  for (int kp = 0; kp < 128; ++kp) {
    uint32_t xv0 = xs[(tr * 4 + 0) * 132 + kp];
    uint32_t xv1 = xs[(tr * 4 + 1) * 132 + kp];
    uint32_t xv2 = xs[(tr * 4 + 2) * 132 + kp];
    uint32_t xv3 = xs[(tr * 4 + 3) * 132 + kp];
    uint4 wv = *(const uint4*)(W2a + (size_t)kp * 1024);
    acc[0][0] = fdot2(xv0, wv.x, acc[0][0]); acc[0][1] = fdot2(xv0, wv.y, acc[0][1]);
    acc[0][2] = fdot2(xv0, wv.z, acc[0][2]); acc[0][3] = fdot2(xv0, wv.w, acc[0][3]);
    acc[1][0] = fdot2(xv1, wv.x, acc[1][0]); acc[1][1] = fdot2(xv1, wv.y, acc[1][1]);
    acc[1][2] = fdot2(xv1, wv.z, acc[1][2]); acc[1][3] = fdot2(xv1, wv.w, acc[1][3]);
    acc[2][0] = fdot2(xv2, wv.x, acc[2][0]); acc[2][1] = fdot2(xv2, wv.y, acc[2][1]);
    acc[2][2] = fdot2(xv2, wv.z, acc[2][2]); acc[2][3] = fdot2(xv2, wv.w, acc[2][3]);
    acc[3][0] = fdot2(xv3, wv.x, acc[3][0]); acc[3][1] = fdot2(xv3, wv.y, acc[3][1]);
    acc[3][2] = fdot2(xv3, wv.z, acc[3][2]); acc[3][3] = fdot2(xv3, wv.w, acc[3][3]);
  }

  const float* bias = a == 0 ? bd : a == 1 ? bz : a == 2 ? br : bh;
  uint16_t* dst = a == 0 ? g_gamma : a == 1 ? g_xz : a == 2 ? g_xr : g_xh;
  float b0 = bias[j0], b1 = bias[j0 + 1], b2 = bias[j0 + 2], b3 = bias[j0 + 3];
#pragma unroll
  for (int i = 0; i < 4; ++i) {
    int n = rg * 64 + tr * 4 + i;
    int b = n >> 9, t = n & 511;
    float p0 = acc[i][0] + b0, p1 = acc[i][1] + b1;
    float p2 = acc[i][2] + b2, p3 = acc[i][3] + b3;
    if (a == 0) {
      p0 = __expf(-fmaxf(p0, 0.f)); p1 = __expf(-fmaxf(p1, 0.f));
      p2 = __expf(-fmaxf(p2, 0.f)); p3 = __expf(-fmaxf(p3, 0.f));
    }
    uint32_t* o = (uint32_t*)(dst + (((size_t)(t * 64 + b)) << 10) + j0);
    o[0] = pack2(p0, p1);
    o[1] = pack2(p2, p3);
  }
}

// ---- persistent scan ---------------------------------------------------
// 256 WGs x 256 threads, 1/CU. WG (rt = wg&3, c = wg>>2) owns tile rows
// [rt*16,+16) x cols [c*16,+16). All exchange is within the 64-WG group
// sharing rt -> 4 independent flag barriers.

__global__ __launch_bounds__(256) void scan_k(
    const float* __restrict__ Uz, const float* __restrict__ Ur,
    const float* __restrict__ Uh,
    const uint16_t* __restrict__ g_gamma, const uint16_t* __restrict__ g_xz,
    const uint16_t* __restrict__ g_xr, const uint16_t* __restrict__ g_xh,
    uint16_t* __restrict__ hdec, uint16_t* __restrict__ RH,
    float* __restrict__ out, unsigned* __restrict__ flags) {
  __shared__ uint16_t ut[3][16][UT_STRIDE];  // U^T col-slices, f16
  __shared__ float redz[1024];
  __shared__ float redr[1024];
  __shared__ float hdl[256];  // own hdec tile, f32

  const int tid = threadIdx.x;
  const int wg = blockIdx.x;
  const int rt = wg & 3;
  const int c = wg >> 2;
  const int lane = tid & 63, wv = tid >> 6;
  const int r16 = lane & 15, q = lane >> 4;
  const int col = c * 16 + r16;
  const int myslot = (rt * 64 + c) * 16;

  // one-time: stage U^T slices (cols [c*16,+16), all K) into LDS
  {
    const float* Us[3] = {Uz, Ur, Uh};
#pragma unroll
    for (int m = 0; m < 3; ++m) {
      const float* src = Us[m] + c * 16;
      for (int i = tid; i < 16 * 1024; i += 256) {
        int k = i >> 4, cc = i & 15;
        ut[m][cc][k] = f2h(src[(size_t)k * 1024 + cc]);
      }
    }
  }
  hdl[tid] = 0.f;
  __syncthreads();

  float hdreg[4] = {0.f, 0.f, 0.f, 0.f};
  f32x4 zacc = {0.f, 0.f, 0.f, 0.f};
  unsigned ep = 0;
  uint4 a[8];

  for (int t = 0; t < NT; ++t) {
    // ---- P1: z,r gates. Wave wv loads K-quarter of the 16-row hdec panel,
    // computes partials for BOTH gates; LDS reduce. ----
    {
      const uint16_t* gA = hdec + ((size_t)(rt * 16 + r16) << 10) + wv * 256 + q * 8;
#pragma unroll
      for (int ks = 0; ks < 8; ++ks) a[ks] = ld_cg_b128(gA + ks * 32);
    }
    const uint16_t* bz_p = &ut[0][r16][wv * 256 + q * 8];
    const uint16_t* br_p = &ut[1][r16][wv * 256 + q * 8];
    half8 bzf[8], brf[8];
#pragma unroll
    for (int ks = 0; ks < 8; ++ks) {
      bzf[ks] = *(const half8*)(bz_p + ks * 32);
      brf[ks] = *(const half8*)(br_p + ks * 32);
    }
    asm volatile("s_waitcnt vmcnt(0)" ::: "memory");
    __builtin_amdgcn_sched_barrier(0);
    f32x4 az = {0.f, 0.f, 0.f, 0.f}, ar = {0.f, 0.f, 0.f, 0.f};
#pragma unroll
    for (int ks = 0; ks < 8; ++ks) {
      half8 av = __builtin_bit_cast(half8, a[ks]);
      az = __builtin_amdgcn_mfma_f32_16x16x32_f16(av, bzf[ks], az, 0, 0, 0);
      ar = __builtin_amdgcn_mfma_f32_16x16x32_f16(av, brf[ks], ar, 0, 0, 0);
    }
#pragma unroll
    for (int j = 0; j < 4; ++j) {
      redz[wv * 256 + j * 64 + lane] = az[j];
      redr[wv * 256 + j * 64 + lane] = ar[j];
    }
    __syncthreads();
    if (wv == 0) {
#pragma unroll
      for (int j = 0; j < 4; ++j) {
        float s = redz[j * 64 + lane] + redz[256 + j * 64 + lane] +
                  redz[512 + j * 64 + lane] + redz[768 + j * 64 + lane];
        int b = rt * 16 + q * 4 + j;
        float xz = h2f(g_xz[(((size_t)(t * 64 + b)) << 10) + col]);
        zacc[j] = 1.f / (1.f + __expf(-(xz + s)));
      }
    } else if (wv == 2) {
#pragma unroll
      for (int j = 0; j < 4; ++j) {
        float s = redr[j * 64 + lane] + redr[256 + j * 64 + lane] +
                  redr[512 + j * 64 + lane] + redr[768 + j * 64 + lane];
        int b = rt * 16 + q * 4 + j;
        float xr = h2f(g_xr[(((size_t)(t * 64 + b)) << 10) + col]);
        float r = 1.f / (1.f + __expf(-(xr + s)));
        float rh = r * hdl[(q * 4 + j) * 16 + r16];
        st_cg_b16(RH + (((size_t)b) << 10) + col, (uint32_t)f2h(rh));
      }
      asm volatile("s_waitcnt vmcnt(0)" ::: "memory");
    }
    // group barrier (64 WGs sharing rt)
    ++ep;
    __syncthreads();
    if (tid == 0)
      __hip_atomic_store(flags + myslot, ep, __ATOMIC_RELAXED, __HIP_MEMORY_SCOPE_AGENT);
    if (tid < 64) {
      while (__hip_atomic_load(flags + (rt * 64 + tid) * 16, __ATOMIC_RELAXED,
                               __HIP_MEMORY_SCOPE_AGENT) < ep)
        __builtin_amdgcn_s_sleep(1);
    }
    __syncthreads();

    // ---- P2: hprop = tanh(xh + RH @ Uh), combine, publish hdec(t+1) ----
    {
      const uint16_t* gA2 = RH + ((size_t)(rt * 16 + r16) << 10) + wv * 256 + q * 8;
#pragma unroll
      for (int ks = 0; ks < 8; ++ks) a[ks] = ld_cg_b128(gA2 + ks * 32);
    }
    const uint16_t* bh_p = &ut[2][r16][wv * 256 + q * 8];
#pragma unroll
    for (int ks = 0; ks < 8; ++ks) bzf[ks] = *(const half8*)(bh_p + ks * 32);
    asm volatile("s_waitcnt vmcnt(0)" ::: "memory");
    __builtin_amdgcn_sched_barrier(0);
    f32x4 ah = {0.f, 0.f, 0.f, 0.f};
#pragma unroll
    for (int ks = 0; ks < 8; ++ks)
      ah = __builtin_amdgcn_mfma_f32_16x16x32_f16(__builtin_bit_cast(half8, a[ks]),
                                                  bzf[ks], ah, 0, 0, 0);
#pragma unroll
    for (int j = 0; j < 4; ++j) redz[wv * 256 + j * 64 + lane] = ah[j];
    __syncthreads();
    if (wv == 0) {
#pragma unroll
      for (int j = 0; j < 4; ++j) {
        float s = redz[j * 64 + lane] + redz[256 + j * 64 + lane] +
                  redz[512 + j * 64 + lane] + redz[768 + j * 64 + lane];
        int b = rt * 16 + q * 4 + j;
        size_t tb = (((size_t)(t * 64 + b)) << 10) + col;
        float hp = tanhf(h2f(g_xh[tb]) + s);
        float z = zacc[j];
        float h = (1.f - z) * hdreg[j] + z * hp;
        out[((size_t)b * NT + t) * NH + col] = h;
        float hdn = 0.f;
        if (t + 1 < NT) {
          float g = h2f(g_gamma[(((size_t)((t + 1) * 64 + b)) << 10) + col]);
          hdn = g * h;
          st_cg_b16(hdec + (((size_t)b) << 10) + col, (uint32_t)f2h(hdn));
        }
        hdreg[j] = hdn;
        hdl[(q * 4 + j) * 16 + r16] = hdn;
      }
      asm volatile("s_waitcnt vmcnt(0)" ::: "memory");
    }
    if (t + 1 < NT) {
      ++ep;
      __syncthreads();
      if (tid == 0)
        __hip_atomic_store(flags + myslot, ep, __ATOMIC_RELAXED, __HIP_MEMORY_SCOPE_AGENT);
      if (tid < 64) {
        while (__hip_atomic_load(flags + (rt * 64 + tid) * 16, __ATOMIC_RELAXED,
                                 __HIP_MEMORY_SCOPE_AGENT) < ep)
          __builtin_amdgcn_s_sleep(1);
      }
      __syncthreads();
    }
  }
}

// ---- launch ------------------------------------------------------------

extern "C" void kernel_launch(void* const* d_in, const int* in_sizes, int n_in,
                              void* d_out, int out_size, void* d_ws, size_t ws_size,
                              hipStream_t stream) {
  const float* x  = (const float*)d_in[0];
  const float* Wd = (const float*)d_in[1];
  const float* bd = (const float*)d_in[2];
  const float* Wz = (const float*)d_in[3];
  const float* Wr = (const float*)d_in[4];
  const float* Wh = (const float*)d_in[5];
  const float* Uz = (const float*)d_in[6];
  const float* Ur = (const float*)d_in[7];
  const float* Uh = (const float*)d_in[8];
  const float* bz = (const float*)d_in[9];
  const float* br = (const float*)d_in[10];
  const float* bh = (const float*)d_in[11];
  float* out = (float*)d_out;

  char* ws = (char*)d_ws;
  size_t off = 0;
  auto take = [&](size_t bytes) -> char* {
    char* p = ws + off;
    off = (off + bytes + 255) & ~(size_t)255;
    return p;
  };
  uint32_t* x2 = (uint32_t*)take((size_t)32768 * 128 * 4);    // 16 MiB
  uint32_t* W2 = (uint32_t*)take((size_t)4 * 128 * 1024 * 4); // 2 MiB
  uint16_t* g_gamma = (uint16_t*)take((size_t)NT * NB * NH * 2); // 64 MiB
  uint16_t* g_xz   = (uint16_t*)take((size_t)NT * NB * NH * 2);
  uint16_t* g_xr   = (uint16_t*)take((size_t)NT * NB * NH * 2);
  uint16_t* g_xh   = (uint16_t*)take((size_t)NT * NB * NH * 2);
  uint16_t* hdec   = (uint16_t*)take((size_t)NB * NH * 2);
  uint16_t* RHb    = (uint16_t*)take((size_t)NB * NH * 2);
  unsigned* flags  = (unsigned*)take(4 * 64 * 16 * 4);  // 16 KiB, 64B stride
  (void)ws_size; (void)in_sizes; (void)n_in; (void)out_size;

  hipMemsetAsync(hdec, 0, (size_t)NB * NH * 2, stream);
  hipMemsetAsync(flags, 0, 4 * 64 * 16 * 4, stream);

  pack_x_k<<<2048, 256, 0, stream>>>((const float2*)x, x2, 32768 * 128);
  pack_rows_k<<<512, 256, 0, stream>>>(Wd, W2 + 0 * (128 * 1024), ND);
  pack_rows_k<<<512, 256, 0, stream>>>(Wz, W2 + 1 * (128 * 1024), ND);
  pack_rows_k<<<512, 256, 0, stream>>>(Wr, W2 + 2 * (128 * 1024), ND);
  pack_rows_k<<<512, 256, 0, stream>>>(Wh, W2 + 3 * (128 * 1024), ND);

  proj_k<<<32768, 256, 0, stream>>>(x2, W2, bd, bz, br, bh,
                                    g_gamma, g_xz, g_xr, g_xh);

  scan_k<<<256, 256, 0, stream>>>(Uz, Ur, Uh, g_gamma, g_xz, g_xr, g_xh,
                                  hdec, RHb, out, flags);
}

// Round 5
// 5390.202 us; speedup vs baseline: 3.7003x; 1.1415x over previous
//
#include <hip/hip_runtime.h>
#include <cstdint>
#include <cstddef>

// GRU-D: B=64, T=512, D=256, H=1024.
// v5: barrier-free persistent scan. 8 groups x 32 WGs (by blockIdx, placement-
// independent). Exchange via epoch-tagged dwords (tag<<16 | f16) with sc0 sc1
// loads/stores -> one MALL RT per exchange, no flags/fences/atomics.
// U weights live in registers (192 VGPR/wave); LDS only A-panels + reduce.

#define NB 64
#define NT 512
#define ND 256
#define NH 1024

typedef _Float16 h2_t __attribute__((ext_vector_type(2)));
typedef _Float16 half8 __attribute__((ext_vector_type(8)));
typedef float f32x4 __attribute__((ext_vector_type(4)));

__device__ __forceinline__ float fdot2(uint32_t a, uint32_t b, float acc) {
  h2_t ha = __builtin_bit_cast(h2_t, a);
  h2_t hb = __builtin_bit_cast(h2_t, b);
#if __has_builtin(__builtin_amdgcn_fdot2)
  return __builtin_amdgcn_fdot2(ha, hb, acc, false);
#else
  return acc + (float)ha[0] * (float)hb[0] + (float)ha[1] * (float)hb[1];
#endif
}

__device__ __forceinline__ uint32_t pack2(float a, float b) {
  h2_t v; v[0] = (_Float16)a; v[1] = (_Float16)b;
  return __builtin_bit_cast(uint32_t, v);
}
__device__ __forceinline__ uint16_t f2h(float x) {
  _Float16 v = (_Float16)x; return __builtin_bit_cast(uint16_t, v);
}
__device__ __forceinline__ float h2f(uint16_t u) {
  return (float)__builtin_bit_cast(_Float16, u);
}

// device-coherent (bypass L1+L2, served by MALL)
__device__ __forceinline__ uint4 ld_cg_b128(const uint32_t* p) {
  uint4 v;
  asm volatile("global_load_dwordx4 %0, %1, off sc0 sc1" : "=v"(v) : "v"(p) : "memory");
  return v;
}
__device__ __forceinline__ void st_cg_b32(uint32_t* p, uint32_t v) {
  asm volatile("global_store_dword %0, %1, off sc0 sc1" :: "v"(p), "v"(v) : "memory");
}

// ---- pack kernels ------------------------------------------------------

__global__ void pack_x_k(const float2* __restrict__ x, uint32_t* __restrict__ x2, int n) {
  int stride = gridDim.x * blockDim.x;
  for (int i = blockIdx.x * blockDim.x + threadIdx.x; i < n; i += stride) {
    float2 v = x[i];
    x2[i] = pack2(v.x, v.y);
  }
}

// src [K][1024] f32 -> dst [K/2][1024] f16x2 (pairs along K) — for W
__global__ void pack_rows_k(const float* __restrict__ src, uint32_t* __restrict__ dst, int K) {
  int n = (K >> 1) * NH;
  int stride = gridDim.x * blockDim.x;
  for (int i = blockIdx.x * blockDim.x + threadIdx.x; i < n; i += stride) {
    int kp = i >> 10, j = i & 1023;
    dst[i] = pack2(src[(2 * kp) * NH + j], src[(2 * kp + 1) * NH + j]);
  }
}

// U [1024][1024] f32 -> UT [1024 cols][1024 k] f16. 64x64 LDS tiles.
__global__ __launch_bounds__(256) void transpose_f2h_k(
    const float* __restrict__ src, uint16_t* __restrict__ dst) {
  __shared__ uint16_t lt[64][68];
  int tr = blockIdx.x & 15, tc = blockIdx.x >> 4;
  int tid = threadIdx.x;
  int r0 = tid >> 6, cc = tid & 63;
#pragma unroll
  for (int it = 0; it < 16; ++it) {
    int r = it * 4 + r0;
    lt[cc][r] = f2h(src[(size_t)(tr * 64 + r) * 1024 + tc * 64 + cc]);
  }
  __syncthreads();
#pragma unroll
  for (int it = 0; it < 16; ++it) {
    int c = it * 4 + r0;
    dst[(size_t)(tc * 64 + c) * 1024 + tr * 64 + cc] = lt[c][cc];
  }
}

// ---- phase 1: input projections (proven) -------------------------------
__global__ __launch_bounds__(256) void proj_k(
    const uint32_t* __restrict__ x2, const uint32_t* __restrict__ W2,
    const float* __restrict__ bd, const float* __restrict__ bz,
    const float* __restrict__ br, const float* __restrict__ bh,
    uint16_t* __restrict__ g_gamma, uint16_t* __restrict__ g_xz,
    uint16_t* __restrict__ g_xr, uint16_t* __restrict__ g_xh) {
  __shared__ uint32_t xs[64 * 132];
  int wg = blockIdx.x;
  int rg = wg >> 6;
  int cg = wg & 63;
  int tid = threadIdx.x;

  const uint4* xsrc = (const uint4*)x2 + (size_t)rg * 64 * 32;
#pragma unroll
  for (int w = 0; w < 8; ++w) {
    int f = tid + w * 256;
    int row = f >> 5, q = f & 31;
    *(uint4*)&xs[row * 132 + q * 4] = xsrc[row * 32 + q];
  }
  __syncthreads();

  int a = cg >> 4;
  int j0 = (cg & 15) * 64 + (tid & 15) * 4;
  int tr = tid >> 4;
  const uint32_t* W2a = W2 + (size_t)a * (128 * 1024) + j0;

  float acc[4][4] = {};
#pragma unroll 4
  for (int kp = 0; kp < 128; ++kp) {
    uint32_t xv0 = xs[(tr * 4 + 0) * 132 + kp];
    uint32_t xv1 = xs[(tr * 4 + 1) * 132 + kp];
    uint32_t xv2 = xs[(tr * 4 + 2) * 132 + kp];
    uint32_t xv3 = xs[(tr * 4 + 3) * 132 + kp];
    uint4 wv = *(const uint4*)(W2a + (size_t)kp * 1024);
    acc[0][0] = fdot2(xv0, wv.x, acc[0][0]); acc[0][1] = fdot2(xv0, wv.y, acc[0][1]);
    acc[0][2] = fdot2(xv0, wv.z, acc[0][2]); acc[0][3] = fdot2(xv0, wv.w, acc[0][3]);
    acc[1][0] = fdot2(xv1, wv.x, acc[1][0]); acc[1][1] = fdot2(xv1, wv.y, acc[1][1]);
    acc[1][2] = fdot2(xv1, wv.z, acc[1][2]); acc[1][3] = fdot2(xv1, wv.w, acc[1][3]);
    acc[2][0] = fdot2(xv2, wv.x, acc[2][0]); acc[2][1] = fdot2(xv2, wv.y, acc[2][1]);
    acc[2][2] = fdot2(xv2, wv.z, acc[2][2]); acc[2][3] = fdot2(xv2, wv.w, acc[2][3]);
    acc[3][0] = fdot2(xv3, wv.x, acc[3][0]); acc[3][1] = fdot2(xv3, wv.y, acc[3][1]);
    acc[3][2] = fdot2(xv3, wv.z, acc[3][2]); acc[3][3] = fdot2(xv3, wv.w, acc[3][3]);
  }

  const float* bias = a == 0 ? bd : a == 1 ? bz : a == 2 ? br : bh;
  uint16_t* dst = a == 0 ? g_gamma : a == 1 ? g_xz : a == 2 ? g_xr : g_xh;
  float b0 = bias[j0], b1 = bias[j0 + 1], b2 = bias[j0 + 2], b3 = bias[j0 + 3];
#pragma unroll
  for (int i = 0; i < 4; ++i) {
    int n = rg * 64 + tr * 4 + i;
    int b = n >> 9, t = n & 511;
    float p0 = acc[i][0] + b0, p1 = acc[i][1] + b1;
    float p2 = acc[i][2] + b2, p3 = acc[i][3] + b3;
    if (a == 0) {
      p0 = __expf(-fmaxf(p0, 0.f)); p1 = __expf(-fmaxf(p1, 0.f));
      p2 = __expf(-fmaxf(p2, 0.f)); p3 = __expf(-fmaxf(p3, 0.f));
    }
    uint32_t* o = (uint32_t*)(dst + (((size_t)(t * 64 + b)) << 10) + j0);
    o[0] = pack2(p0, p1);
    o[1] = pack2(p2, p3);
  }
}

// ---- barrier-free tagged scan -----------------------------------------
// Group g = blockIdx&7 owns batch rows [8g,+8); slot = blockIdx>>3 owns cols
// [slot*32,+32). Hbuf/RHbuf: [64 rows][1024 cols] dwords, each = tag<<16|f16.
// Hbuf tag t = h_dec(t) (memset 0 => t=0, h=0). RHbuf tag t+1 written in P1(t).
// Wave w takes K-slice [w*256,+256); B-fragments register-resident.

__global__ __launch_bounds__(256, 1) void scan_k(
    const uint16_t* __restrict__ UzT, const uint16_t* __restrict__ UrT,
    const uint16_t* __restrict__ UhT,
    const uint16_t* __restrict__ g_gamma, const uint16_t* __restrict__ g_xz,
    const uint16_t* __restrict__ g_xr, const uint16_t* __restrict__ g_xh,
    uint32_t* __restrict__ Hbuf, uint32_t* __restrict__ RHbuf,
    float* __restrict__ out) {
  __shared__ uint16_t Hp[9][1032];   // h_dec panel rows 0-7, row 8 = zeros
  __shared__ uint16_t RHp[9][1032];
  __shared__ float red[4][4][256];

  const int tid = threadIdx.x;
  const int g = blockIdx.x & 7;
  const int slot = blockIdx.x >> 3;
  const int c0 = slot * 32;
  const int lane = tid & 63, w = tid >> 6;
  const int r16 = lane & 15, q = lane >> 4;

  for (int i = tid; i < 1032; i += 256) { Hp[8][i] = 0; RHp[8][i] = 0; }

  // ---- one-time: B fragments into registers (per wave: K in [w*256,+256))
  half8 Bz[2][8], Br[2][8], Bh[2][8];
#pragma unroll
  for (int ct = 0; ct < 2; ++ct) {
    const size_t colb = (size_t)(c0 + ct * 16 + r16) * 1024 + w * 256 + q * 8;
#pragma unroll
    for (int kc = 0; kc < 8; ++kc) {
      Bz[ct][kc] = *(const half8*)(UzT + colb + kc * 32);
      Br[ct][kc] = *(const half8*)(UrT + colb + kc * 32);
      Bh[ct][kc] = *(const half8*)(UhT + colb + kc * 32);
    }
  }
  __syncthreads();

  const uint16_t* aprow = Hp[r16 < 8 ? r16 : 8];
  const uint16_t* aprow2 = RHp[r16 < 8 ? r16 : 8];
  const int aoff = w * 256 + q * 8;

  // epilogue geometry: wave ct = w&1; rows erow..erow+3 (valid when lane<32)
  const int ect = w & 1;
  const int ecol = c0 + ect * 16 + r16;
  const int erow = q * 4;

  auto poll_fill = [&](const uint32_t* __restrict__ buf, unsigned exp,
                       uint16_t (&panel)[9][1032]) {
    const uint32_t* base = buf + ((size_t)g << 13) + (size_t)tid * 4;
    uint4 sv[8];
    for (;;) {
#pragma unroll
      for (int i = 0; i < 8; ++i) sv[i] = ld_cg_b128(base + i * 1024);
      asm volatile("s_waitcnt vmcnt(0)" ::: "memory");
      __builtin_amdgcn_sched_barrier(0);
      unsigned ok = 1u;
#pragma unroll
      for (int i = 0; i < 8; ++i) {
        ok &= (unsigned)((sv[i].x >> 16) == exp);
        ok &= (unsigned)((sv[i].y >> 16) == exp);
        ok &= (unsigned)((sv[i].z >> 16) == exp);
        ok &= (unsigned)((sv[i].w >> 16) == exp);
      }
      if (__all((int)ok)) break;
      __builtin_amdgcn_s_sleep(1);
    }
#pragma unroll
    for (int i = 0; i < 8; ++i) {
      int idx = tid + i * 256;  // row = idx>>8 in [0,8), col4 = (idx&255)*4
      uint32_t p0 = (sv[i].x & 0xffffu) | (sv[i].y << 16);
      uint32_t p1 = (sv[i].z & 0xffffu) | (sv[i].w << 16);
      *(uint2*)&panel[idx >> 8][(idx & 255) * 4] = make_uint2(p0, p1);
    }
  };

  for (int t = 0; t < NT; ++t) {
    // (a) prefetch gate streams for this step (clamped rows for lane>=32)
    float xzv[4], xrv[4], xhv[4], gmv[4];
    {
      const int tg = (t + 1 < NT) ? t + 1 : t;
#pragma unroll
      for (int j = 0; j < 4; ++j) {
        int rr = erow + j; if (rr > 7) rr = 7;
        size_t base = (((size_t)(t * 64 + g * 8 + rr)) << 10) + ecol;
        if (w < 2) {
          xzv[j] = h2f(g_xz[base]);
          xhv[j] = h2f(g_xh[base]);
          gmv[j] = h2f(g_gamma[(((size_t)(tg * 64 + g * 8 + rr)) << 10) + ecol]);
          xrv[j] = 0.f;
        } else {
          xrv[j] = h2f(g_xr[base]);
          xzv[j] = xhv[j] = gmv[j] = 0.f;
        }
      }
    }

    // (b) poll h_dec(t) panel -> Hp
    poll_fill(Hbuf, (unsigned)t, Hp);
    __syncthreads();  // (c) Hp ready; red free

    // (d) P1 MFMA: z and r partials over K-slice
    f32x4 az0 = {0.f,0.f,0.f,0.f}, az1 = {0.f,0.f,0.f,0.f};
    f32x4 ar0 = {0.f,0.f,0.f,0.f}, ar1 = {0.f,0.f,0.f,0.f};
#pragma unroll
    for (int kc = 0; kc < 8; ++kc) {
      half8 av = *(const half8*)(aprow + aoff + kc * 32);
      az0 = __builtin_amdgcn_mfma_f32_16x16x32_f16(av, Bz[0][kc], az0, 0, 0, 0);
      az1 = __builtin_amdgcn_mfma_f32_16x16x32_f16(av, Bz[1][kc], az1, 0, 0, 0);
      ar0 = __builtin_amdgcn_mfma_f32_16x16x32_f16(av, Br[0][kc], ar0, 0, 0, 0);
      ar1 = __builtin_amdgcn_mfma_f32_16x16x32_f16(av, Br[1][kc], ar1, 0, 0, 0);
    }
    *(f32x4*)&red[w][0][lane * 4] = az0;
    *(f32x4*)&red[w][1][lane * 4] = az1;
    *(f32x4*)&red[w][2][lane * 4] = ar0;
    *(f32x4*)&red[w][3][lane * 4] = ar1;
    __syncthreads();

    // (e) reduce tile w; epilogue: waves 0,1 keep z,hd; waves 2,3 publish RH
    float zk[4] = {0.f,0.f,0.f,0.f}, hdk[4] = {0.f,0.f,0.f,0.f};
    {
      f32x4 s = *(const f32x4*)&red[0][w][lane * 4];
      s += *(const f32x4*)&red[1][w][lane * 4];
      s += *(const f32x4*)&red[2][w][lane * 4];
      s += *(const f32x4*)&red[3][w][lane * 4];
      if (lane < 32) {
        if (w < 2) {
#pragma unroll
          for (int j = 0; j < 4; ++j) {
            zk[j] = 1.f / (1.f + __expf(-(xzv[j] + s[j])));
            hdk[j] = h2f(Hp[erow + j][ecol]);
          }
        } else {
#pragma unroll
          for (int j = 0; j < 4; ++j) {
            float rg = 1.f / (1.f + __expf(-(xrv[j] + s[j])));
            float hd = h2f(Hp[erow + j][ecol]);
            st_cg_b32(RHbuf + (((size_t)(g * 8 + erow + j)) << 10) + ecol,
                      ((unsigned)(t + 1) << 16) | (uint32_t)f2h(rg * hd));
          }
        }
      }
    }

    // (f) poll RH(t) panel -> RHp
    poll_fill(RHbuf, (unsigned)(t + 1), RHp);
    __syncthreads();  // RHp ready; red consumed by all

    // (g) P2 MFMA: hprop partials
    f32x4 ah0 = {0.f,0.f,0.f,0.f}, ah1 = {0.f,0.f,0.f,0.f};
#pragma unroll
    for (int kc = 0; kc < 8; ++kc) {
      half8 av = *(const half8*)(aprow2 + aoff + kc * 32);
      ah0 = __builtin_amdgcn_mfma_f32_16x16x32_f16(av, Bh[0][kc], ah0, 0, 0, 0);
      ah1 = __builtin_amdgcn_mfma_f32_16x16x32_f16(av, Bh[1][kc], ah1, 0, 0, 0);
    }
    *(f32x4*)&red[w][0][lane * 4] = ah0;
    *(f32x4*)&red[w][1][lane * 4] = ah1;
    __syncthreads();

    // (h) reduce + combine + publish h_dec(t+1) and out (waves 0,1)
    if (w < 2) {
      f32x4 s = *(const f32x4*)&red[0][w][lane * 4];
      s += *(const f32x4*)&red[1][w][lane * 4];
      s += *(const f32x4*)&red[2][w][lane * 4];
      s += *(const f32x4*)&red[3][w][lane * 4];
      if (lane < 32) {
#pragma unroll
        for (int j = 0; j < 4; ++j) {
          float hp = tanhf(xhv[j] + s[j]);
          float h = (1.f - zk[j]) * hdk[j] + zk[j] * hp;
          int b = g * 8 + erow + j;
          out[((size_t)b * NT + t) * NH + ecol] = h;
          if (t + 1 < NT)
            st_cg_b32(Hbuf + (((size_t)b) << 10) + ecol,
                      ((unsigned)(t + 1) << 16) | (uint32_t)f2h(gmv[j] * h));
        }
      }
    }
    // no trailing barrier needed: next (c) sync protects red; Hp writes in
    // next (b) only race with (e)-reads which are pre-(f)-sync.
  }
}

// ---- launch ------------------------------------------------------------

extern "C" void kernel_launch(void* const* d_in, const int* in_sizes, int n_in,
                              void* d_out, int out_size, void* d_ws, size_t ws_size,
                              hipStream_t stream) {
  const float* x  = (const float*)d_in[0];
  const float* Wd = (const float*)d_in[1];
  const float* bd = (const float*)d_in[2];
  const float* Wz = (const float*)d_in[3];
  const float* Wr = (const float*)d_in[4];
  const float* Wh = (const float*)d_in[5];
  const float* Uz = (const float*)d_in[6];
  const float* Ur = (const float*)d_in[7];
  const float* Uh = (const float*)d_in[8];
  const float* bz = (const float*)d_in[9];
  const float* br = (const float*)d_in[10];
  const float* bh = (const float*)d_in[11];
  float* out = (float*)d_out;

  char* ws = (char*)d_ws;
  size_t off = 0;
  auto take = [&](size_t bytes) -> char* {
    char* p = ws + off;
    off = (off + bytes + 255) & ~(size_t)255;
    return p;
  };
  uint32_t* x2  = (uint32_t*)take((size_t)32768 * 128 * 4);    // 16 MiB
  uint32_t* W2  = (uint32_t*)take((size_t)4 * 128 * 1024 * 4); // 2 MiB
  uint16_t* UzT = (uint16_t*)take((size_t)1024 * 1024 * 2);    // 2 MiB
  uint16_t* UrT = (uint16_t*)take((size_t)1024 * 1024 * 2);
  uint16_t* UhT = (uint16_t*)take((size_t)1024 * 1024 * 2);
  uint16_t* g_gamma = (uint16_t*)take((size_t)NT * NB * NH * 2); // 64 MiB
  uint16_t* g_xz   = (uint16_t*)take((size_t)NT * NB * NH * 2);
  uint16_t* g_xr   = (uint16_t*)take((size_t)NT * NB * NH * 2);
  uint16_t* g_xh   = (uint16_t*)take((size_t)NT * NB * NH * 2);
  uint32_t* Hbuf   = (uint32_t*)take((size_t)NB * NH * 4);     // 256 KiB
  uint32_t* RHbuf  = (uint32_t*)take((size_t)NB * NH * 4);     // 256 KiB
  (void)ws_size; (void)in_sizes; (void)n_in; (void)out_size;

  hipMemsetAsync(Hbuf, 0, (size_t)NB * NH * 4, stream);   // tag 0, h=0
  hipMemsetAsync(RHbuf, 0, (size_t)NB * NH * 4, stream);  // tag 0 (< exp 1)

  pack_x_k<<<2048, 256, 0, stream>>>((const float2*)x, x2, 32768 * 128);
  pack_rows_k<<<512, 256, 0, stream>>>(Wd, W2 + 0 * (128 * 1024), ND);
  pack_rows_k<<<512, 256, 0, stream>>>(Wz, W2 + 1 * (128 * 1024), ND);
  pack_rows_k<<<512, 256, 0, stream>>>(Wr, W2 + 2 * (128 * 1024), ND);
  pack_rows_k<<<512, 256, 0, stream>>>(Wh, W2 + 3 * (128 * 1024), ND);
  transpose_f2h_k<<<256, 256, 0, stream>>>(Uz, UzT);
  transpose_f2h_k<<<256, 256, 0, stream>>>(Ur, UrT);
  transpose_f2h_k<<<256, 256, 0, stream>>>(Uh, UhT);

  proj_k<<<32768, 256, 0, stream>>>(x2, W2, bd, bz, br, bh,
                                    g_gamma, g_xz, g_xr, g_xh);

  scan_k<<<256, 256, 0, stream>>>(UzT, UrT, UhT, g_gamma, g_xz, g_xr, g_xh,
                                  Hbuf, RHbuf, out);
}